// Round 13
// baseline (729.168 us; speedup 1.0000x reference)
//
#include <hip/hip_runtime.h>
#include <hip/hip_bf16.h>

typedef __attribute__((ext_vector_type(8))) __bf16 bx8;
typedef __attribute__((ext_vector_type(4))) float  fx4;

#define ROWS 8192   // B*S
#define HID  1024
#define MEMN 8192

// global_load_lds, 16B per lane; LDS dest = wave-uniform base + lane*16
#define GLDS(gp, lp) __builtin_amdgcn_global_load_lds( \
    (const __attribute__((address_space(1))) void*)(gp), \
    (__attribute__((address_space(3))) void*)(lp), 16, 0, 0)

#define MEMFENCE asm volatile("" ::: "memory")

// ---------------------------------------------------------------------------
// fp32 -> bf16 elementwise convert
// ---------------------------------------------------------------------------
__global__ __launch_bounds__(256)
void f32_to_bf16_vec(const float* __restrict__ in, __bf16* __restrict__ out)
{
    const size_t i = ((size_t)blockIdx.x * 256 + threadIdx.x) * 8;
    fx4 a = *(const fx4*)(in + i);
    fx4 b = *(const fx4*)(in + i + 4);
    bx8 u;
    u[0] = (__bf16)a[0]; u[1] = (__bf16)a[1]; u[2] = (__bf16)a[2]; u[3] = (__bf16)a[3];
    u[4] = (__bf16)b[0]; u[5] = (__bf16)b[1]; u[6] = (__bf16)b[2]; u[7] = (__bf16)b[3];
    *(bx8*)(out + i) = u;
}

// ---------------------------------------------------------------------------
// fp32 [R][C] -> bf16 [C][R] transpose (64x64 tiles via LDS).
// SCALE != nullptr: multiply element (r,c) by scale[r] (per input-row scale).
// ---------------------------------------------------------------------------
__global__ __launch_bounds__(256)
void transpose_f32_to_bf16(const float* __restrict__ in, __bf16* __restrict__ out,
                           const float* __restrict__ scale, int R, int C)
{
    __shared__ float t[64][65];
    const int tid = threadIdx.x;
    const int r0 = blockIdx.y * 64;
    const int c0 = blockIdx.x * 64;
    const int lr = tid >> 4;
    const int lc = (tid & 15) * 4;
#pragma unroll
    for (int p = 0; p < 4; ++p) {
        const int rr = p * 16 + lr;
        const fx4 v = *(const fx4*)(in + (size_t)(r0 + rr) * C + c0 + lc);
        t[rr][lc + 0] = v[0]; t[rr][lc + 1] = v[1];
        t[rr][lc + 2] = v[2]; t[rr][lc + 3] = v[3];
    }
    __syncthreads();
    const int oc = tid >> 2;
    const int ob = (tid & 3) * 16;
    bx8 u0, u1;
    if (scale) {
#pragma unroll
        for (int j = 0; j < 8; ++j) {
            u0[j] = (__bf16)(t[ob + j][oc]     * scale[r0 + ob + j]);
            u1[j] = (__bf16)(t[ob + 8 + j][oc] * scale[r0 + ob + 8 + j]);
        }
    } else {
#pragma unroll
        for (int j = 0; j < 8; ++j) {
            u0[j] = (__bf16)t[ob + j][oc];
            u1[j] = (__bf16)t[ob + 8 + j][oc];
        }
    }
    *(bx8*)(out + (size_t)(c0 + oc) * R + r0 + ob)     = u0;
    *(bx8*)(out + (size_t)(c0 + oc) * R + r0 + ob + 8) = u1;
}

// ---------------------------------------------------------------------------
// invert_rows: inv[r] = 1 / sum_{c<nchunk} part[c*8192 + r].  r < 8192.
// ---------------------------------------------------------------------------
__global__ __launch_bounds__(256)
void invert_rows(const float* __restrict__ part, float* __restrict__ inv,
                 int nchunk)
{
    const int r = blockIdx.x * 256 + threadIdx.x;
    float s = 0.f;
    for (int c = 0; c < nchunk; ++c) s += part[(size_t)c * 8192 + r];
    inv[r] = 1.0f / s;
}

// ---------------------------------------------------------------------------
// gemm8: round-3 verified NT GEMM core (ring-4 LDS, one counted vmcnt + one
// barrier per K-tile, PMC-verified conflict-free swizzle). Epilogue modes:
//   MODE 2: f32 out = c + add[idx]                          (write PV)
//   MODE 3: bf16 out = exp(c + bias[col]); block row-sums of exp, reduced in
//           LDS, written COALESCED -> ((float*)add)[(tn>>8)*8192 + tm + row]
//   MODE 4: bf16 out = exp(c + bias[row]); block col-sums of exp, reduced in
//           LDS, written COALESCED -> ((float*)add)[(tm>>8)*8192 + tn + col]
//   MODE 5: f32 out = c * bias[row]                         (read PV, 1/rowsum)
// Round-12 lesson: scattered 4B partial stores caused +151 MB HBM write
// amplification; this version emits one 1KB contiguous chunk per block.
// ---------------------------------------------------------------------------
template <int BM, int BN, int MODE>
__global__ __launch_bounds__(512)
void gemm8(const __bf16* __restrict__ A, const __bf16* __restrict__ B,
           const float* __restrict__ bias, const float* __restrict__ add,
           void* __restrict__ out, int N, int K, int nBN)
{
    constexpr int ASZ = BM * 64;
    constexpr int BSZ = BN * 64;
    constexpr int RA  = BM / 128;
    constexpr int RB  = BN / 128;
    constexpr int L   = RA + RB;
    constexpr int RWM = BM / 2, RWN = BN / 4;
    constexpr int FM  = RWM / 16, FN = RWN / 16;

    __shared__ __align__(16) char smem[4 * (ASZ + BSZ)];
    __shared__ float lds_red[256][4];          // epilogue partial-sum reduce

    const int tid = threadIdx.x;
    const int wid = tid >> 6;
    const int ln  = tid & 63;
    const int fl  = ln & 15;
    const int fh  = ln >> 4;
    const int wr  = wid >> 2;
    const int wc  = wid & 3;

    const int nwg = gridDim.x;
    const int bid = blockIdx.x;
    const int wg  = (bid & 7) * (nwg >> 3) + (bid >> 3);
    const int tm  = (wg / nBN) * BM;
    const int tn  = (wg % nBN) * BN;

    const int NT = K / 32;

    const __bf16* Ag[RA];
    const __bf16* Bg[RB];
#pragma unroll
    for (int R = 0; R < RA; ++R) {
        const int p = R * 512 + tid;
        Ag[R] = A + (size_t)(tm + (p >> 2)) * K + ((p & 3) ^ ((p >> 3) & 3)) * 8;
    }
#pragma unroll
    for (int R = 0; R < RB; ++R) {
        const int p = R * 512 + tid;
        Bg[R] = B + (size_t)(tn + (p >> 2)) * K + ((p & 3) ^ ((p >> 3) & 3)) * 8;
    }

    auto stage = [&](int t) {
        const int s = t & 3;
        const size_t ko = (size_t)t * 32;
        char* Ad = smem + s * ASZ + wid * 1024;
        char* Bd = smem + 4 * ASZ + s * BSZ + wid * 1024;
#pragma unroll
        for (int R = 0; R < RA; ++R) GLDS(Ag[R] + ko, Ad + R * 8192);
#pragma unroll
        for (int R = 0; R < RB; ++R) GLDS(Bg[R] + ko, Bd + R * 8192);
    };

    fx4 acc[FM][FN] = {};

    stage(0);
    if (NT > 1) stage(1);

    for (int t = 0; t < NT; ++t) {
        if (t == NT - 1) {
            asm volatile("s_waitcnt vmcnt(0)" ::: "memory");
        } else {
            asm volatile("s_waitcnt vmcnt(%0)" :: "i"(L) : "memory");
        }
        __builtin_amdgcn_s_barrier();
        MEMFENCE;
        if (t + 2 < NT) stage(t + 2);

        const char* Ab = smem + (t & 3) * ASZ;
        const char* Bb = smem + 4 * ASZ + (t & 3) * BSZ;
        bx8 fa[FM], fb[FN];
#pragma unroll
        for (int mi = 0; mi < FM; ++mi) {
            const int r = wr * RWM + mi * 16 + fl;
            fa[mi] = *(const bx8*)(Ab + r * 64 + ((fh ^ ((r >> 1) & 3)) << 4));
        }
#pragma unroll
        for (int ni = 0; ni < FN; ++ni) {
            const int c = wc * RWN + ni * 16 + fl;
            fb[ni] = *(const bx8*)(Bb + c * 64 + ((fh ^ ((c >> 1) & 3)) << 4));
        }
        __builtin_amdgcn_s_setprio(1);
#pragma unroll
        for (int mi = 0; mi < FM; ++mi)
#pragma unroll
            for (int ni = 0; ni < FN; ++ni)
                acc[mi][ni] = __builtin_amdgcn_mfma_f32_16x16x32_bf16(
                    fa[mi], fb[ni], acc[mi][ni], 0, 0, 0);
        __builtin_amdgcn_s_setprio(0);
    }

    // epilogue: C/D layout col = lane&15, row = (lane>>4)*4 + reg
    if constexpr (MODE == 3) {
        __bf16* O   = (__bf16*)out;
        float* part = (float*)add;                 // [32][8192]
#pragma unroll
        for (int mi = 0; mi < FM; ++mi) {
            float ps[4] = {0.f, 0.f, 0.f, 0.f};
            const int gr0 = tm + wr * RWM + mi * 16 + fh * 4;
#pragma unroll
            for (int ni = 0; ni < FN; ++ni) {
                const int gc = tn + wc * RWN + ni * 16 + fl;
                const float bv = bias[gc];
                fx4 c = acc[mi][ni];
#pragma unroll
                for (int j = 0; j < 4; ++j) {
                    const float e = __expf(c[j] + bv);
                    O[(size_t)(gr0 + j) * N + gc] = (__bf16)e;
                    ps[j] += e;
                }
            }
#pragma unroll
            for (int j = 0; j < 4; ++j) {
#pragma unroll
                for (int off = 1; off <= 8; off <<= 1)
                    ps[j] += __shfl_xor(ps[j], off, 64);
                if (fl == 0)
                    lds_red[wr * RWM + mi * 16 + fh * 4 + j][wc] = ps[j];
            }
        }
        __syncthreads();
        if (tid < 256) {
            const float s = (lds_red[tid][0] + lds_red[tid][1])
                          + (lds_red[tid][2] + lds_red[tid][3]);
            part[(size_t)(tn >> 8) * 8192 + tm + tid] = s;
        }
    } else if constexpr (MODE == 4) {
        __bf16* O    = (__bf16*)out;
        float* partc = (float*)add;                // [32][8192]
#pragma unroll
        for (int ni = 0; ni < FN; ++ni) {
            const int gc = tn + wc * RWN + ni * 16 + fl;
            float qs = 0.f;
#pragma unroll
            for (int mi = 0; mi < FM; ++mi) {
                const int gr0 = tm + wr * RWM + mi * 16 + fh * 4;
                fx4 c = acc[mi][ni];
#pragma unroll
                for (int j = 0; j < 4; ++j) {
                    const float e = __expf(c[j] + bias[gr0 + j]);
                    O[(size_t)(gr0 + j) * N + gc] = (__bf16)e;
                    qs += e;
                }
            }
            qs += __shfl_xor(qs, 16, 64);
            qs += __shfl_xor(qs, 32, 64);
            if (fh == 0)
                lds_red[wc * RWN + ni * 16 + fl][wr] = qs;
        }
        __syncthreads();
        if (tid < 256) {
            const float s = lds_red[tid][0] + lds_red[tid][1];
            partc[(size_t)(tm >> 8) * 8192 + tn + tid] = s;
        }
    } else {
#pragma unroll
        for (int mi = 0; mi < FM; ++mi) {
#pragma unroll
            for (int ni = 0; ni < FN; ++ni) {
                const int gr0 = tm + wr * RWM + mi * 16 + fh * 4;
                const int gc  = tn + wc * RWN + ni * 16 + fl;
                fx4 c = acc[mi][ni];
                if constexpr (MODE == 2) {
                    float* O = (float*)out;
#pragma unroll
                    for (int j = 0; j < 4; ++j) {
                        const size_t idx = (size_t)(gr0 + j) * N + gc;
                        O[idx] = c[j] + add[idx];
                    }
                } else {   // MODE 5
                    float* O = (float*)out;
#pragma unroll
                    for (int j = 0; j < 4; ++j)
                        O[(size_t)(gr0 + j) * N + gc] = c[j] * bias[gr0 + j];
                }
            }
        }
    }
}

// ---------------------------------------------------------------------------
// Orchestration. ws layout (176 MiB):
//   xb    [8192,1024] bf16  @ 0
//   slot1 @ 16 MiB : rwb then wwb
//   slot2 @ 32 MiB : memT, then xT*invc
//   W     @ 48 MiB : exp(read logits), then exp(write logits)^T (unnormalized)
// Reduction scratch (coalesced 1KB-chunk writes) in the dead out_mem half of
// d_out: part [32][8192], invr [8192], partc [32][8192], invc [8192] (2.1 MB).
// ---------------------------------------------------------------------------
extern "C" void kernel_launch(void* const* d_in, const int* in_sizes, int n_in,
                              void* d_out, int out_size, void* d_ws, size_t ws_size,
                              hipStream_t stream)
{
    const float* x       = (const float*)d_in[0];
    const float* memory  = (const float*)d_in[1];
    const float* read_w  = (const float*)d_in[2];
    const float* read_b  = (const float*)d_in[3];
    const float* write_w = (const float*)d_in[4];
    const float* write_b = (const float*)d_in[5];

    float* out_read = (float*)d_out;
    float* out_mem  = (float*)d_out + (size_t)MEMN * HID;

    char* p = (char*)d_ws;
    const size_t MiB = 1024 * 1024;
    __bf16* xb    = (__bf16*)(p + 0 * MiB);
    __bf16* slot1 = (__bf16*)(p + 16 * MiB);
    __bf16* slot2 = (__bf16*)(p + 32 * MiB);
    __bf16* W     = (__bf16*)(p + 48 * MiB);

    float* part  = out_mem;                        // 32*8192 floats (1 MB)
    float* invr  = out_mem + 32 * 8192;            // 8192 floats
    float* partc = invr + 8192;                    // 32*8192 floats (1 MB)
    float* invc  = partc + 32 * 8192;              // 8192 floats

    // ---- read path ---------------------------------------------------------
    f32_to_bf16_vec<<<4096, 256, 0, stream>>>(x, xb);
    f32_to_bf16_vec<<<4096, 256, 0, stream>>>(read_w, slot1);
    transpose_f32_to_bf16<<<dim3(HID / 64, ROWS / 64), 256, 0, stream>>>(
        memory, slot2, nullptr, ROWS, HID);
    // W[s][m] = exp(x.rw^T + rb), block row partials -> part (coalesced)
    gemm8<256, 256, 3><<<(ROWS / 256) * (MEMN / 256), 512, 0, stream>>>(
        xb, slot1, read_b, part, W, MEMN, HID, MEMN / 256);
    invert_rows<<<32, 256, 0, stream>>>(part, invr, 32);
    // out_read[s][h] = invr[s] * sum_m W[s,m] mem[m,h]
    gemm8<128, 256, 5><<<(ROWS / 128) * (HID / 256), 512, 0, stream>>>(
        W, slot2, invr, nullptr, out_read, HID, MEMN, HID / 256);

    // ---- write path --------------------------------------------------------
    f32_to_bf16_vec<<<4096, 256, 0, stream>>>(write_w, slot1);
    // W^T[m][s] = exp(ww.x^T + wb[m]), block col partials -> partc (coalesced)
    gemm8<256, 256, 4><<<(MEMN / 256) * (ROWS / 256), 512, 0, stream>>>(
        slot1, xb, write_b, partc, W, ROWS, HID, ROWS / 256);
    invert_rows<<<32, 256, 0, stream>>>(partc, invc, 32);
    // xT[h][s] = x[s][h] * invc[s]
    transpose_f32_to_bf16<<<dim3(HID / 64, ROWS / 64), 256, 0, stream>>>(
        x, slot2, invc, ROWS, HID);
    // out_mem[m][h] = memory[m,h] + sum_s W^T[m,s] * xT[h,s]
    gemm8<128, 256, 2><<<(MEMN / 128) * (HID / 256), 512, 0, stream>>>(
        W, slot2, nullptr, memory, out_mem, HID, ROWS, HID / 256);
}

// Round 14
// 667.047 us; speedup vs baseline: 1.0931x; 1.0931x over previous
//
#include <hip/hip_runtime.h>
#include <hip/hip_bf16.h>

typedef __attribute__((ext_vector_type(8))) __bf16 bx8;
typedef __attribute__((ext_vector_type(4))) float  fx4;

#define ROWS 8192   // B*S
#define HID  1024
#define MEMN 8192

// global_load_lds, 16B per lane; LDS dest = wave-uniform base + lane*16
#define GLDS(gp, lp) __builtin_amdgcn_global_load_lds( \
    (const __attribute__((address_space(1))) void*)(gp), \
    (__attribute__((address_space(3))) void*)(lp), 16, 0, 0)

#define MEMFENCE asm volatile("" ::: "memory")

// ---------------------------------------------------------------------------
// fp32 -> bf16 elementwise convert
// ---------------------------------------------------------------------------
__global__ __launch_bounds__(256)
void f32_to_bf16_vec(const float* __restrict__ in, __bf16* __restrict__ out)
{
    const size_t i = ((size_t)blockIdx.x * 256 + threadIdx.x) * 8;
    fx4 a = *(const fx4*)(in + i);
    fx4 b = *(const fx4*)(in + i + 4);
    bx8 u;
    u[0] = (__bf16)a[0]; u[1] = (__bf16)a[1]; u[2] = (__bf16)a[2]; u[3] = (__bf16)a[3];
    u[4] = (__bf16)b[0]; u[5] = (__bf16)b[1]; u[6] = (__bf16)b[2]; u[7] = (__bf16)b[3];
    *(bx8*)(out + i) = u;
}

// ---------------------------------------------------------------------------
// fp32 [R][C] -> bf16 [C][R] transpose (64x64 tiles via LDS).
// SCALE != nullptr: multiply element (r,c) by scale[r] (per input-row scale).
// ---------------------------------------------------------------------------
__global__ __launch_bounds__(256)
void transpose_f32_to_bf16(const float* __restrict__ in, __bf16* __restrict__ out,
                           const float* __restrict__ scale, int R, int C)
{
    __shared__ float t[64][65];
    const int tid = threadIdx.x;
    const int r0 = blockIdx.y * 64;
    const int c0 = blockIdx.x * 64;
    const int lr = tid >> 4;
    const int lc = (tid & 15) * 4;
#pragma unroll
    for (int p = 0; p < 4; ++p) {
        const int rr = p * 16 + lr;
        const fx4 v = *(const fx4*)(in + (size_t)(r0 + rr) * C + c0 + lc);
        t[rr][lc + 0] = v[0]; t[rr][lc + 1] = v[1];
        t[rr][lc + 2] = v[2]; t[rr][lc + 3] = v[3];
    }
    __syncthreads();
    const int oc = tid >> 2;
    const int ob = (tid & 3) * 16;
    bx8 u0, u1;
    if (scale) {
#pragma unroll
        for (int j = 0; j < 8; ++j) {
            u0[j] = (__bf16)(t[ob + j][oc]     * scale[r0 + ob + j]);
            u1[j] = (__bf16)(t[ob + 8 + j][oc] * scale[r0 + ob + 8 + j]);
        }
    } else {
#pragma unroll
        for (int j = 0; j < 8; ++j) {
            u0[j] = (__bf16)t[ob + j][oc];
            u1[j] = (__bf16)t[ob + 8 + j][oc];
        }
    }
    *(bx8*)(out + (size_t)(c0 + oc) * R + r0 + ob)     = u0;
    *(bx8*)(out + (size_t)(c0 + oc) * R + r0 + ob + 8) = u1;
}

// ---------------------------------------------------------------------------
// colsum_partial: part[chunk][s] = sum over 128 rows of W[m][s].
// grid (4, 64): x = 2048-col range, y = 128-row chunk. Coalesced bx8 reads.
// ---------------------------------------------------------------------------
__global__ __launch_bounds__(256)
void colsum_partial(const __bf16* __restrict__ W, float* __restrict__ part)
{
    const int s0 = blockIdx.x * 2048 + threadIdx.x * 8;
    const int m0 = blockIdx.y * 128;
    fx4 a0 = {}, a1 = {};
    for (int r = 0; r < 128; ++r) {
        bx8 u = *(const bx8*)(W + (size_t)(m0 + r) * MEMN + s0);
        a0[0] += (float)u[0]; a0[1] += (float)u[1];
        a0[2] += (float)u[2]; a0[3] += (float)u[3];
        a1[0] += (float)u[4]; a1[1] += (float)u[5];
        a1[2] += (float)u[6]; a1[3] += (float)u[7];
    }
    *(fx4*)(part + (size_t)blockIdx.y * MEMN + s0)     = a0;
    *(fx4*)(part + (size_t)blockIdx.y * MEMN + s0 + 4) = a1;
}

// ---------------------------------------------------------------------------
// colsum_finalize: invc[s] = 1 / sum_c part[c][s].  grid 32 x 256 threads.
// ---------------------------------------------------------------------------
__global__ __launch_bounds__(256)
void colsum_finalize(const float* __restrict__ part, float* __restrict__ invc)
{
    const int s = blockIdx.x * 256 + threadIdx.x;
    float t = 0.f;
#pragma unroll 8
    for (int c = 0; c < 64; ++c) t += part[(size_t)c * MEMN + s];
    invc[s] = 1.0f / t;
}

// ---------------------------------------------------------------------------
// gemm8: round-3 verified NT GEMM core (ring-4 LDS, one counted vmcnt + one
// barrier per K-tile, PMC-verified conflict-free swizzle). Epilogue modes:
//   MODE 2: f32 out = c + add[idx]                  (write PV)
//   MODE 3: bf16 out = exp(c + bias[col])           (read logits, unnormalized)
//   MODE 4: bf16 out = exp(c + bias[row])           (write logits -> W^T)
//   MODE 5: f32 out = c / rowsum, rowsum computed IN-KERNEL via a ones-operand
//           MFMA (acc_sum = A x ones summed over the full K = whole W row).
//           No separate rowsum kernel, no extra global traffic.
// ---------------------------------------------------------------------------
template <int BM, int BN, int MODE>
__global__ __launch_bounds__(512)
void gemm8(const __bf16* __restrict__ A, const __bf16* __restrict__ B,
           const float* __restrict__ bias, const float* __restrict__ add,
           void* __restrict__ out, int N, int K, int nBN)
{
    constexpr int ASZ = BM * 64;
    constexpr int BSZ = BN * 64;
    constexpr int RA  = BM / 128;
    constexpr int RB  = BN / 128;
    constexpr int L   = RA + RB;
    constexpr int RWM = BM / 2, RWN = BN / 4;
    constexpr int FM  = RWM / 16, FN = RWN / 16;

    __shared__ __align__(16) char smem[4 * (ASZ + BSZ)];

    const int tid = threadIdx.x;
    const int wid = tid >> 6;
    const int ln  = tid & 63;
    const int fl  = ln & 15;
    const int fh  = ln >> 4;
    const int wr  = wid >> 2;
    const int wc  = wid & 3;

    const int nwg = gridDim.x;
    const int bid = blockIdx.x;
    const int wg  = (bid & 7) * (nwg >> 3) + (bid >> 3);
    const int tm  = (wg / nBN) * BM;
    const int tn  = (wg % nBN) * BN;

    const int NT = K / 32;

    const __bf16* Ag[RA];
    const __bf16* Bg[RB];
#pragma unroll
    for (int R = 0; R < RA; ++R) {
        const int p = R * 512 + tid;
        Ag[R] = A + (size_t)(tm + (p >> 2)) * K + ((p & 3) ^ ((p >> 3) & 3)) * 8;
    }
#pragma unroll
    for (int R = 0; R < RB; ++R) {
        const int p = R * 512 + tid;
        Bg[R] = B + (size_t)(tn + (p >> 2)) * K + ((p & 3) ^ ((p >> 3) & 3)) * 8;
    }

    auto stage = [&](int t) {
        const int s = t & 3;
        const size_t ko = (size_t)t * 32;
        char* Ad = smem + s * ASZ + wid * 1024;
        char* Bd = smem + 4 * ASZ + s * BSZ + wid * 1024;
#pragma unroll
        for (int R = 0; R < RA; ++R) GLDS(Ag[R] + ko, Ad + R * 8192);
#pragma unroll
        for (int R = 0; R < RB; ++R) GLDS(Bg[R] + ko, Bd + R * 8192);
    };

    fx4 acc[FM][FN] = {};
    fx4 acc_sum[FM] = {};          // MODE 5 only: row sums via ones-MFMA
    bx8 ones;
#pragma unroll
    for (int j = 0; j < 8; ++j) ones[j] = (__bf16)1.0f;

    stage(0);
    if (NT > 1) stage(1);

    for (int t = 0; t < NT; ++t) {
        if (t == NT - 1) {
            asm volatile("s_waitcnt vmcnt(0)" ::: "memory");
        } else {
            asm volatile("s_waitcnt vmcnt(%0)" :: "i"(L) : "memory");
        }
        __builtin_amdgcn_s_barrier();
        MEMFENCE;
        if (t + 2 < NT) stage(t + 2);

        const char* Ab = smem + (t & 3) * ASZ;
        const char* Bb = smem + 4 * ASZ + (t & 3) * BSZ;
        bx8 fa[FM], fb[FN];
#pragma unroll
        for (int mi = 0; mi < FM; ++mi) {
            const int r = wr * RWM + mi * 16 + fl;
            fa[mi] = *(const bx8*)(Ab + r * 64 + ((fh ^ ((r >> 1) & 3)) << 4));
        }
#pragma unroll
        for (int ni = 0; ni < FN; ++ni) {
            const int c = wc * RWN + ni * 16 + fl;
            fb[ni] = *(const bx8*)(Bb + c * 64 + ((fh ^ ((c >> 1) & 3)) << 4));
        }
        __builtin_amdgcn_s_setprio(1);
#pragma unroll
        for (int mi = 0; mi < FM; ++mi)
#pragma unroll
            for (int ni = 0; ni < FN; ++ni)
                acc[mi][ni] = __builtin_amdgcn_mfma_f32_16x16x32_bf16(
                    fa[mi], fb[ni], acc[mi][ni], 0, 0, 0);
        if constexpr (MODE == 5) {
#pragma unroll
            for (int mi = 0; mi < FM; ++mi)
                acc_sum[mi] = __builtin_amdgcn_mfma_f32_16x16x32_bf16(
                    fa[mi], ones, acc_sum[mi], 0, 0, 0);
        }
        __builtin_amdgcn_s_setprio(0);
    }

    // epilogue: C/D layout col = lane&15, row = (lane>>4)*4 + reg
#pragma unroll
    for (int mi = 0; mi < FM; ++mi) {
#pragma unroll
        for (int ni = 0; ni < FN; ++ni) {
            const int gr0 = tm + wr * RWM + mi * 16 + fh * 4;
            const int gc  = tn + wc * RWN + ni * 16 + fl;
            fx4 c = acc[mi][ni];
            if constexpr (MODE == 2) {
                float* O = (float*)out;
#pragma unroll
                for (int j = 0; j < 4; ++j) {
                    const size_t idx = (size_t)(gr0 + j) * N + gc;
                    O[idx] = c[j] + add[idx];
                }
            } else if constexpr (MODE == 3) {
                __bf16* O = (__bf16*)out;
                const float bv = bias[gc];
#pragma unroll
                for (int j = 0; j < 4; ++j)
                    O[(size_t)(gr0 + j) * N + gc] = (__bf16)__expf(c[j] + bv);
            } else if constexpr (MODE == 4) {
                __bf16* O = (__bf16*)out;
#pragma unroll
                for (int j = 0; j < 4; ++j)
                    O[(size_t)(gr0 + j) * N + gc] =
                        (__bf16)__expf(c[j] + bias[gr0 + j]);
            } else {   // MODE 5: self-normalizing (acc_sum holds row sums)
                float* O = (float*)out;
#pragma unroll
                for (int j = 0; j < 4; ++j)
                    O[(size_t)(gr0 + j) * N + gc] = c[j] / acc_sum[mi][j];
            }
        }
    }
}

// ---------------------------------------------------------------------------
// Orchestration. ws layout (176 MiB):
//   xb    [8192,1024] bf16  @ 0
//   slot1 @ 16 MiB : rwb (16MB) -> wwb (16MB) -> colsum part (2MB) +
//                    invc (32KB @ +4MiB)
//   slot2 @ 32 MiB : memT, then xT*invc
//   W     @ 48 MiB : exp(read logits), then exp(write logits)^T (unnormalized)
// Read-path normalization is computed INSIDE the PV GEMM (ones-MFMA row sums);
// write-path colsum stays as separate kernels (fused form regressed, r12/r13).
// ---------------------------------------------------------------------------
extern "C" void kernel_launch(void* const* d_in, const int* in_sizes, int n_in,
                              void* d_out, int out_size, void* d_ws, size_t ws_size,
                              hipStream_t stream)
{
    const float* x       = (const float*)d_in[0];
    const float* memory  = (const float*)d_in[1];
    const float* read_w  = (const float*)d_in[2];
    const float* read_b  = (const float*)d_in[3];
    const float* write_w = (const float*)d_in[4];
    const float* write_b = (const float*)d_in[5];

    float* out_read = (float*)d_out;
    float* out_mem  = (float*)d_out + (size_t)MEMN * HID;

    char* p = (char*)d_ws;
    const size_t MiB = 1024 * 1024;
    __bf16* xb    = (__bf16*)(p + 0 * MiB);
    __bf16* slot1 = (__bf16*)(p + 16 * MiB);
    __bf16* slot2 = (__bf16*)(p + 32 * MiB);
    __bf16* W     = (__bf16*)(p + 48 * MiB);
    float*  part  = (float*)(p + 16 * MiB);          // after wwb dead (2 MB)
    float*  invc  = (float*)(p + 20 * MiB);          // 32 KB

    // ---- read path ---------------------------------------------------------
    f32_to_bf16_vec<<<4096, 256, 0, stream>>>(x, xb);
    f32_to_bf16_vec<<<4096, 256, 0, stream>>>(read_w, slot1);
    transpose_f32_to_bf16<<<dim3(HID / 64, ROWS / 64), 256, 0, stream>>>(
        memory, slot2, nullptr, ROWS, HID);
    // W[s][m] = exp(x.rw^T + rb)   (unnormalized softmax numerators)
    gemm8<256, 256, 3><<<(ROWS / 256) * (MEMN / 256), 512, 0, stream>>>(
        xb, slot1, read_b, nullptr, W, MEMN, HID, MEMN / 256);
    // out_read[s][h] = (sum_m W[s,m] mem[m,h]) / (sum_m W[s,m])  [in-kernel]
    gemm8<128, 256, 5><<<(ROWS / 128) * (HID / 256), 512, 0, stream>>>(
        W, slot2, nullptr, nullptr, out_read, HID, MEMN, HID / 256);

    // ---- write path --------------------------------------------------------
    f32_to_bf16_vec<<<4096, 256, 0, stream>>>(write_w, slot1);
    // W^T[m][s] = exp(ww.x^T + wb[m])  -- transposed logits, no transpose pass
    gemm8<256, 256, 4><<<(MEMN / 256) * (ROWS / 256), 512, 0, stream>>>(
        slot1, xb, write_b, nullptr, W, ROWS, HID, ROWS / 256);
    colsum_partial<<<dim3(4, 64), 256, 0, stream>>>(W, part);
    colsum_finalize<<<32, 256, 0, stream>>>(part, invc);
    // xT[h][s] = x[s][h] * invc[s]
    transpose_f32_to_bf16<<<dim3(HID / 64, ROWS / 64), 256, 0, stream>>>(
        x, slot2, invc, ROWS, HID);
    // out_mem[m][h] = memory[m,h] + sum_s W^T[m,s] * xT[h,s]
    gemm8<128, 256, 2><<<(MEMN / 128) * (HID / 256), 512, 0, stream>>>(
        W, slot2, nullptr, memory, out_mem, HID, ROWS, HID / 256);
}

// Round 15
// 544.656 us; speedup vs baseline: 1.3388x; 1.2247x over previous
//
#include <hip/hip_runtime.h>
#include <hip/hip_bf16.h>
#include <hip/hip_fp8.h>

typedef __attribute__((ext_vector_type(8))) __bf16 bx8;
typedef __attribute__((ext_vector_type(4))) float  fx4;
typedef __attribute__((ext_vector_type(4))) int    ix4;
typedef __attribute__((ext_vector_type(8))) int    ix8;

#define ROWS 8192   // B*S
#define HID  1024
#define MEMN 8192

// global_load_lds, 16B per lane; LDS dest = wave-uniform base + lane*16
#define GLDS(gp, lp) __builtin_amdgcn_global_load_lds( \
    (const __attribute__((address_space(1))) void*)(gp), \
    (__attribute__((address_space(3))) void*)(lp), 16, 0, 0)

#define MEMFENCE asm volatile("" ::: "memory")

__device__ __forceinline__ unsigned char f2q(float f) {
    __hip_fp8_e4m3 q(f);
    return (unsigned char)q.__x;
}
__device__ __forceinline__ float q2f(unsigned char b) {
    __hip_fp8_e4m3 q;
    q.__x = (__hip_fp8_storage_t)b;
    return (float)q;
}

// ---------------------------------------------------------------------------
// fp32 -> bf16 elementwise convert
// ---------------------------------------------------------------------------
__global__ __launch_bounds__(256)
void f32_to_bf16_vec(const float* __restrict__ in, __bf16* __restrict__ out)
{
    const size_t i = ((size_t)blockIdx.x * 256 + threadIdx.x) * 8;
    fx4 a = *(const fx4*)(in + i);
    fx4 b = *(const fx4*)(in + i + 4);
    bx8 u;
    u[0] = (__bf16)a[0]; u[1] = (__bf16)a[1]; u[2] = (__bf16)a[2]; u[3] = (__bf16)a[3];
    u[4] = (__bf16)b[0]; u[5] = (__bf16)b[1]; u[6] = (__bf16)b[2]; u[7] = (__bf16)b[3];
    *(bx8*)(out + i) = u;
}

// ---------------------------------------------------------------------------
// fp32 [R][C] -> fp8 [C][R] transpose (64x64 tiles via LDS).
// scale != nullptr: multiply element (r,c) by scale[r]; then by premul.
// ---------------------------------------------------------------------------
__global__ __launch_bounds__(256)
void transpose_f32_to_fp8(const float* __restrict__ in,
                          unsigned char* __restrict__ out,
                          const float* __restrict__ scale, float premul,
                          int R, int C)
{
    __shared__ float t[64][65];
    const int tid = threadIdx.x;
    const int r0 = blockIdx.y * 64;
    const int c0 = blockIdx.x * 64;
    const int lr = tid >> 4;
    const int lc = (tid & 15) * 4;
#pragma unroll
    for (int p = 0; p < 4; ++p) {
        const int rr = p * 16 + lr;
        const fx4 v = *(const fx4*)(in + (size_t)(r0 + rr) * C + c0 + lc);
        t[rr][lc + 0] = v[0]; t[rr][lc + 1] = v[1];
        t[rr][lc + 2] = v[2]; t[rr][lc + 3] = v[3];
    }
    __syncthreads();
    const int oc = tid >> 2;
    const int ob = (tid & 3) * 16;
    unsigned char b[16];
#pragma unroll
    for (int j = 0; j < 16; ++j) {
        float v = t[ob + j][oc];
        if (scale) v *= scale[r0 + ob + j];
        b[j] = f2q(v * premul);
    }
    *(ix4*)(out + (size_t)(c0 + oc) * R + r0 + ob) = *(ix4*)b;
}

// ---------------------------------------------------------------------------
// colsum_partial_q: part[chunk][s] = sum over 128 rows of fp8 W[m][s].
// grid (2, 64). 16 cols per thread, coalesced 16B loads.
// ---------------------------------------------------------------------------
__global__ __launch_bounds__(256)
void colsum_partial_q(const unsigned char* __restrict__ W,
                      float* __restrict__ part)
{
    const int s0 = blockIdx.x * 4096 + threadIdx.x * 16;
    const int m0 = blockIdx.y * 128;
    float a[16];
#pragma unroll
    for (int j = 0; j < 16; ++j) a[j] = 0.f;
    for (int r = 0; r < 128; ++r) {
        ix4 u = *(const ix4*)(W + (size_t)(m0 + r) * MEMN + s0);
        const unsigned char* ub = (const unsigned char*)&u;
#pragma unroll
        for (int j = 0; j < 16; ++j) a[j] += q2f(ub[j]);
    }
#pragma unroll
    for (int q = 0; q < 4; ++q)
        *(fx4*)(part + (size_t)blockIdx.y * MEMN + s0 + q * 4) =
            *(fx4*)(a + q * 4);
}

// ---------------------------------------------------------------------------
// colsum_finalize: invc[s] = 1 / sum_c part[c][s].  grid 32 x 256 threads.
// ---------------------------------------------------------------------------
__global__ __launch_bounds__(256)
void colsum_finalize(const float* __restrict__ part, float* __restrict__ invc)
{
    const int s = blockIdx.x * 256 + threadIdx.x;
    float t = 0.f;
#pragma unroll 8
    for (int c = 0; c < 64; ++c) t += part[(size_t)c * MEMN + s];
    invc[s] = 1.0f / t;
}

// ---------------------------------------------------------------------------
// gemm8: round-3 verified bf16 NT GEMM core (ring-4, counted vmcnt + one
// barrier per K-tile, PMC-verified swizzle). Logits only now:
//   MODE 3: fp8 out = e4m3(exp(c + bias[col]))   (read logits -> W)
//   MODE 4: fp8 out = e4m3(exp(c + bias[row]))   (write logits -> W^T)
// ---------------------------------------------------------------------------
template <int BM, int BN, int MODE>
__global__ __launch_bounds__(512)
void gemm8(const __bf16* __restrict__ A, const __bf16* __restrict__ B,
           const float* __restrict__ bias, void* __restrict__ out,
           int N, int K, int nBN)
{
    constexpr int ASZ = BM * 64;
    constexpr int BSZ = BN * 64;
    constexpr int RA  = BM / 128;
    constexpr int RB  = BN / 128;
    constexpr int L   = RA + RB;
    constexpr int RWM = BM / 2, RWN = BN / 4;
    constexpr int FM  = RWM / 16, FN = RWN / 16;

    __shared__ __align__(16) char smem[4 * (ASZ + BSZ)];

    const int tid = threadIdx.x;
    const int wid = tid >> 6;
    const int ln  = tid & 63;
    const int fl  = ln & 15;
    const int fh  = ln >> 4;
    const int wr  = wid >> 2;
    const int wc  = wid & 3;

    const int nwg = gridDim.x;
    const int bid = blockIdx.x;
    const int wg  = (bid & 7) * (nwg >> 3) + (bid >> 3);
    const int tm  = (wg / nBN) * BM;
    const int tn  = (wg % nBN) * BN;

    const int NT = K / 32;

    const __bf16* Ag[RA];
    const __bf16* Bg[RB];
#pragma unroll
    for (int R = 0; R < RA; ++R) {
        const int p = R * 512 + tid;
        Ag[R] = A + (size_t)(tm + (p >> 2)) * K + ((p & 3) ^ ((p >> 3) & 3)) * 8;
    }
#pragma unroll
    for (int R = 0; R < RB; ++R) {
        const int p = R * 512 + tid;
        Bg[R] = B + (size_t)(tn + (p >> 2)) * K + ((p & 3) ^ ((p >> 3) & 3)) * 8;
    }

    auto stage = [&](int t) {
        const int s = t & 3;
        const size_t ko = (size_t)t * 32;
        char* Ad = smem + s * ASZ + wid * 1024;
        char* Bd = smem + 4 * ASZ + s * BSZ + wid * 1024;
#pragma unroll
        for (int R = 0; R < RA; ++R) GLDS(Ag[R] + ko, Ad + R * 8192);
#pragma unroll
        for (int R = 0; R < RB; ++R) GLDS(Bg[R] + ko, Bd + R * 8192);
    };

    fx4 acc[FM][FN] = {};

    stage(0);
    if (NT > 1) stage(1);

    for (int t = 0; t < NT; ++t) {
        if (t == NT - 1) {
            asm volatile("s_waitcnt vmcnt(0)" ::: "memory");
        } else {
            asm volatile("s_waitcnt vmcnt(%0)" :: "i"(L) : "memory");
        }
        __builtin_amdgcn_s_barrier();
        MEMFENCE;
        if (t + 2 < NT) stage(t + 2);

        const char* Ab = smem + (t & 3) * ASZ;
        const char* Bb = smem + 4 * ASZ + (t & 3) * BSZ;
        bx8 fa[FM], fb[FN];
#pragma unroll
        for (int mi = 0; mi < FM; ++mi) {
            const int r = wr * RWM + mi * 16 + fl;
            fa[mi] = *(const bx8*)(Ab + r * 64 + ((fh ^ ((r >> 1) & 3)) << 4));
        }
#pragma unroll
        for (int ni = 0; ni < FN; ++ni) {
            const int c = wc * RWN + ni * 16 + fl;
            fb[ni] = *(const bx8*)(Bb + c * 64 + ((fh ^ ((c >> 1) & 3)) << 4));
        }
        __builtin_amdgcn_s_setprio(1);
#pragma unroll
        for (int mi = 0; mi < FM; ++mi)
#pragma unroll
            for (int ni = 0; ni < FN; ++ni)
                acc[mi][ni] = __builtin_amdgcn_mfma_f32_16x16x32_bf16(
                    fa[mi], fb[ni], acc[mi][ni], 0, 0, 0);
        __builtin_amdgcn_s_setprio(0);
    }

    // epilogue: C/D layout col = lane&15, row = (lane>>4)*4 + reg
    unsigned char* O = (unsigned char*)out;
#pragma unroll
    for (int mi = 0; mi < FM; ++mi) {
#pragma unroll
        for (int ni = 0; ni < FN; ++ni) {
            const int gr0 = tm + wr * RWM + mi * 16 + fh * 4;
            const int gc  = tn + wc * RWN + ni * 16 + fl;
            fx4 c = acc[mi][ni];
            if constexpr (MODE == 3) {
                const float bv = bias[gc];
#pragma unroll
                for (int j = 0; j < 4; ++j)
                    O[(size_t)(gr0 + j) * N + gc] = f2q(__expf(c[j] + bv));
            } else {   // MODE 4
#pragma unroll
                for (int j = 0; j < 4; ++j)
                    O[(size_t)(gr0 + j) * N + gc] =
                        f2q(__expf(c[j] + bias[gr0 + j]));
            }
        }
    }
}

// ---------------------------------------------------------------------------
// gemm8q: MX-fp8 NT GEMM for the two PV GEMMs (K = 8192).
// 128x256 tile, BK=128 (one mfma_scale_f32_16x16x128_f8f6f4 K-step), 512 thr
// = 8 waves (2Mx4N), wave tile 64x64 (acc[4][4]).  All MX scales = 1.0
// (e8m0 = 127) -> pure fp8 e4m3 math at 2x the bf16 MFMA rate and half the
// LDS/staging bytes.  Ring-3 LDS (144 KiB); round-3 counted-vmcnt ledger with
// L=6 (stage = 2 A-rounds + 4 B-rounds of 8 KiB).  Swizzle: rows are 128 B =
// 8 granules; LDS granule g of row r holds source k-granule g^(r&7) (both
// sides, involution); fragment read for k-block fh reads granules
// (2fh)^(r&7),(2fh+1)^(r&7) -> each 16-lane group spreads over 8 granule
// positions = minimal bank aliasing.
//   MODE 2: out = c*oscale + add[idx]      (write PV; oscale = 1/8192)
//   MODE 5: out = c / rowsum               (read PV; rowsum via ones-MFMA)
// ---------------------------------------------------------------------------
template <int MODE>
__global__ __launch_bounds__(512)
void gemm8q(const unsigned char* __restrict__ A,
            const unsigned char* __restrict__ B,
            const float* __restrict__ add, float* __restrict__ out,
            int N, int K, int nBN, float oscale)
{
    constexpr int ASZ = 128 * 128;    // 16 KiB per A slot
    constexpr int BSZ = 256 * 128;    // 32 KiB per B slot
    __shared__ __align__(16) char smem[3 * (ASZ + BSZ)];   // 144 KiB
    char* const As = smem;
    char* const Bs = smem + 3 * ASZ;

    const int tid = threadIdx.x;
    const int wid = tid >> 6;
    const int ln  = tid & 63;
    const int fl  = ln & 15;
    const int fh  = ln >> 4;
    const int wr  = wid >> 2;          // 0..1 -> rows wr*64
    const int wc  = wid & 3;           // 0..3 -> cols wc*64

    const int nwg = gridDim.x;
    const int bid = blockIdx.x;
    const int wg  = (bid & 7) * (nwg >> 3) + (bid >> 3);
    const int tm  = (wg / nBN) * 128;
    const int tn  = (wg % nBN) * 256;
    const int NT  = K >> 7;            // K/128

    // staging: thread t covers LDS granule t of each 8 KiB round
    // (row = 64*round + t>>3, lds granule t&7); src granule = (t&7)^((t>>3)&7)
    const int trow = tid >> 3;
    const int tsrc = ((tid & 7) ^ ((tid >> 3) & 7)) * 16;
    const unsigned char* Ag[2];
    const unsigned char* Bg[4];
#pragma unroll
    for (int r = 0; r < 2; ++r)
        Ag[r] = A + (size_t)(tm + 64 * r + trow) * K + tsrc;
#pragma unroll
    for (int r = 0; r < 4; ++r)
        Bg[r] = B + (size_t)(tn + 64 * r + trow) * K + tsrc;

    auto stage = [&](int t) {
        const int s = t % 3;
        const size_t ko = (size_t)t * 128;
#pragma unroll
        for (int r = 0; r < 2; ++r)
            GLDS(Ag[r] + ko, As + s * ASZ + r * 8192 + wid * 1024);
#pragma unroll
        for (int r = 0; r < 4; ++r)
            GLDS(Bg[r] + ko, Bs + s * BSZ + r * 8192 + wid * 1024);
    };

    fx4 acc[4][4] = {};
    fx4 accs[4] = {};                  // MODE 5: row sums via ones-MFMA
    ix8 ones;
#pragma unroll
    for (int j = 0; j < 8; ++j) ones[j] = 0x38383838;   // fp8 e4m3 1.0 x4

    stage(0);
    stage(1);

    for (int t = 0; t < NT; ++t) {
        if (t == NT - 1) asm volatile("s_waitcnt vmcnt(0)" ::: "memory");
        else             asm volatile("s_waitcnt vmcnt(6)" ::: "memory");
        __builtin_amdgcn_s_barrier();
        MEMFENCE;
        if (t + 2 < NT) stage(t + 2);

        const char* Ab = As + (t % 3) * ASZ;
        const char* Bb = Bs + (t % 3) * BSZ;

        ix8 fa[4], fb[4];
#pragma unroll
        for (int mi = 0; mi < 4; ++mi) {
            const int r  = wr * 64 + mi * 16 + fl;
            const int g0 = (2 * fh) ^ (r & 7);
            const int g1 = (2 * fh + 1) ^ (r & 7);
            ix4 lo = *(const ix4*)(Ab + r * 128 + g0 * 16);
            ix4 hi = *(const ix4*)(Ab + r * 128 + g1 * 16);
            fa[mi][0] = lo[0]; fa[mi][1] = lo[1]; fa[mi][2] = lo[2]; fa[mi][3] = lo[3];
            fa[mi][4] = hi[0]; fa[mi][5] = hi[1]; fa[mi][6] = hi[2]; fa[mi][7] = hi[3];
        }
#pragma unroll
        for (int ni = 0; ni < 4; ++ni) {
            const int c  = wc * 64 + ni * 16 + fl;
            const int g0 = (2 * fh) ^ (c & 7);
            const int g1 = (2 * fh + 1) ^ (c & 7);
            ix4 lo = *(const ix4*)(Bb + c * 128 + g0 * 16);
            ix4 hi = *(const ix4*)(Bb + c * 128 + g1 * 16);
            fb[ni][0] = lo[0]; fb[ni][1] = lo[1]; fb[ni][2] = lo[2]; fb[ni][3] = lo[3];
            fb[ni][4] = hi[0]; fb[ni][5] = hi[1]; fb[ni][6] = hi[2]; fb[ni][7] = hi[3];
        }
        __builtin_amdgcn_s_setprio(1);
#pragma unroll
        for (int mi = 0; mi < 4; ++mi)
#pragma unroll
            for (int ni = 0; ni < 4; ++ni)
                acc[mi][ni] = __builtin_amdgcn_mfma_scale_f32_16x16x128_f8f6f4(
                    fa[mi], fb[ni], acc[mi][ni], 0, 0, 0, 127, 0, 127);
        if constexpr (MODE == 5) {
#pragma unroll
            for (int mi = 0; mi < 4; ++mi)
                accs[mi] = __builtin_amdgcn_mfma_scale_f32_16x16x128_f8f6f4(
                    fa[mi], ones, accs[mi], 0, 0, 0, 127, 0, 127);
        }
        __builtin_amdgcn_s_setprio(0);
    }

    // epilogue: C/D layout col = lane&15, row = (lane>>4)*4 + reg
#pragma unroll
    for (int mi = 0; mi < 4; ++mi) {
#pragma unroll
        for (int ni = 0; ni < 4; ++ni) {
            const int gr0 = tm + wr * 64 + mi * 16 + fh * 4;
            const int gc  = tn + wc * 64 + ni * 16 + fl;
            fx4 c = acc[mi][ni];
            if constexpr (MODE == 2) {
#pragma unroll
                for (int j = 0; j < 4; ++j) {
                    const size_t idx = (size_t)(gr0 + j) * N + gc;
                    out[idx] = c[j] * oscale + add[idx];
                }
            } else {   // MODE 5: self-normalizing
#pragma unroll
                for (int j = 0; j < 4; ++j)
                    out[(size_t)(gr0 + j) * N + gc] = c[j] / accs[mi][j];
            }
        }
    }
}

// ---------------------------------------------------------------------------
// Orchestration. ws layout (112 MiB used of 176):
//   xb    [8192,1024] bf16 @ 0
//   slot1 @ 16 MiB : rwb (16MB) -> wwb (16MB) -> part (2MB) + invc (@20MiB)
//   slot2 @ 32 MiB : memT fp8 (8MB), then xT*invc*8192 fp8 (8MB)
//   Wq    @ 48 MiB : fp8 exp(read logits) [64MB], then fp8 exp(write logits)^T
// Logits GEMMs: bf16 core, fp8 store. PV GEMMs: MX-fp8 (scales = 1.0).
// xT carries invc*8192 to stay in fp8 range; PV-write epilogue scales by 1/8192.
// ---------------------------------------------------------------------------
extern "C" void kernel_launch(void* const* d_in, const int* in_sizes, int n_in,
                              void* d_out, int out_size, void* d_ws, size_t ws_size,
                              hipStream_t stream)
{
    const float* x       = (const float*)d_in[0];
    const float* memory  = (const float*)d_in[1];
    const float* read_w  = (const float*)d_in[2];
    const float* read_b  = (const float*)d_in[3];
    const float* write_w = (const float*)d_in[4];
    const float* write_b = (const float*)d_in[5];

    float* out_read = (float*)d_out;
    float* out_mem  = (float*)d_out + (size_t)MEMN * HID;

    char* p = (char*)d_ws;
    const size_t MiB = 1024 * 1024;
    __bf16*        xb    = (__bf16*)(p + 0 * MiB);
    __bf16*        slot1 = (__bf16*)(p + 16 * MiB);
    unsigned char* slot2 = (unsigned char*)(p + 32 * MiB);
    unsigned char* Wq    = (unsigned char*)(p + 48 * MiB);
    float*         part  = (float*)(p + 16 * MiB);     // after wwb dead
    float*         invc  = (float*)(p + 20 * MiB);

    // ---- read path ---------------------------------------------------------
    f32_to_bf16_vec<<<4096, 256, 0, stream>>>(x, xb);
    f32_to_bf16_vec<<<4096, 256, 0, stream>>>(read_w, slot1);
    transpose_f32_to_fp8<<<dim3(HID / 64, ROWS / 64), 256, 0, stream>>>(
        memory, slot2, nullptr, 1.0f, ROWS, HID);
    // Wq[s][m] = e4m3(exp(x.rw^T + rb))
    gemm8<256, 256, 3><<<(ROWS / 256) * (MEMN / 256), 512, 0, stream>>>(
        xb, slot1, read_b, Wq, MEMN, HID, MEMN / 256);
    // out_read[s][h] = (sum_m Wq[s,m] memT[h,m]) / (sum_m Wq[s,m])
    gemm8q<5><<<(ROWS / 128) * (HID / 256), 512, 0, stream>>>(
        Wq, slot2, nullptr, out_read, HID, MEMN, HID / 256, 1.0f);

    // ---- write path --------------------------------------------------------
    f32_to_bf16_vec<<<4096, 256, 0, stream>>>(write_w, slot1);
    // Wq^T[m][s] = e4m3(exp(ww.x^T + wb[m]))
    gemm8<256, 256, 4><<<(MEMN / 256) * (ROWS / 256), 512, 0, stream>>>(
        slot1, xb, write_b, Wq, ROWS, HID, ROWS / 256);
    colsum_partial_q<<<dim3(2, 64), 256, 0, stream>>>(Wq, part);
    colsum_finalize<<<32, 256, 0, stream>>>(part, invc);
    // xT[h][s] = e4m3(x[s][h] * invc[s] * 8192)
    transpose_f32_to_fp8<<<dim3(HID / 64, ROWS / 64), 256, 0, stream>>>(
        x, slot2, invc, 8192.0f, ROWS, HID);
    // out_mem[m][h] = memory[m,h] + (1/8192) * sum_s Wq^T[m,s] xT[h,s]
    gemm8q<2><<<(MEMN / 128) * (HID / 256), 512, 0, stream>>>(
        Wq, slot2, memory, out_mem, HID, ROWS, HID / 256, 1.0f / 8192.0f);
}

// Round 16
// 464.533 us; speedup vs baseline: 1.5697x; 1.1725x over previous
//
#include <hip/hip_runtime.h>
#include <hip/hip_bf16.h>
#include <hip/hip_fp8.h>

typedef __attribute__((ext_vector_type(4))) float  fx4;
typedef __attribute__((ext_vector_type(4))) int    ix4;
typedef __attribute__((ext_vector_type(8))) int    ix8;

#define ROWS 8192   // B*S
#define HID  1024
#define MEMN 8192

// global_load_lds, 16B per lane; LDS dest = wave-uniform base + lane*16
#define GLDS(gp, lp) __builtin_amdgcn_global_load_lds( \
    (const __attribute__((address_space(1))) void*)(gp), \
    (__attribute__((address_space(3))) void*)(lp), 16, 0, 0)

#define MEMFENCE asm volatile("" ::: "memory")

__device__ __forceinline__ unsigned char f2q(float f) {
    __hip_fp8_e4m3 q(f);
    return (unsigned char)q.__x;
}
__device__ __forceinline__ float q2f(unsigned char b) {
    __hip_fp8_e4m3 q;
    q.__x = (__hip_fp8_storage_t)b;
    return (float)q;
}

// ---------------------------------------------------------------------------
// fp32 -> fp8 e4m3 elementwise convert (16 elems/thread), value *= premul.
// Exact grid: n = blocks*256*16.
// ---------------------------------------------------------------------------
__global__ __launch_bounds__(256)
void f32_to_fp8_vec(const float* __restrict__ in,
                    unsigned char* __restrict__ out, float premul)
{
    const size_t i = ((size_t)blockIdx.x * 256 + threadIdx.x) * 16;
    unsigned char b[16];
#pragma unroll
    for (int q = 0; q < 4; ++q) {
        fx4 v = *(const fx4*)(in + i + q * 4);
        b[q * 4 + 0] = f2q(v[0] * premul);
        b[q * 4 + 1] = f2q(v[1] * premul);
        b[q * 4 + 2] = f2q(v[2] * premul);
        b[q * 4 + 3] = f2q(v[3] * premul);
    }
    *(ix4*)(out + i) = *(ix4*)b;
}

// ---------------------------------------------------------------------------
// fp32 [R][C] -> fp8 [C][R] transpose (64x64 tiles via LDS).
// scale != nullptr: multiply element (r,c) by scale[r]; then by premul.
// ---------------------------------------------------------------------------
__global__ __launch_bounds__(256)
void transpose_f32_to_fp8(const float* __restrict__ in,
                          unsigned char* __restrict__ out,
                          const float* __restrict__ scale, float premul,
                          int R, int C)
{
    __shared__ float t[64][65];
    const int tid = threadIdx.x;
    const int r0 = blockIdx.y * 64;
    const int c0 = blockIdx.x * 64;
    const int lr = tid >> 4;
    const int lc = (tid & 15) * 4;
#pragma unroll
    for (int p = 0; p < 4; ++p) {
        const int rr = p * 16 + lr;
        const fx4 v = *(const fx4*)(in + (size_t)(r0 + rr) * C + c0 + lc);
        t[rr][lc + 0] = v[0]; t[rr][lc + 1] = v[1];
        t[rr][lc + 2] = v[2]; t[rr][lc + 3] = v[3];
    }
    __syncthreads();
    const int oc = tid >> 2;
    const int ob = (tid & 3) * 16;
    unsigned char b[16];
#pragma unroll
    for (int j = 0; j < 16; ++j) {
        float v = t[ob + j][oc];
        if (scale) v *= scale[r0 + ob + j];
        b[j] = f2q(v * premul);
    }
    *(ix4*)(out + (size_t)(c0 + oc) * R + r0 + ob) = *(ix4*)b;
}

// ---------------------------------------------------------------------------
// colsum_partial_q: part[chunk][s] = sum over 128 rows of fp8 W[m][s].
// grid (2, 64). 16 cols per thread, coalesced 16B loads.
// ---------------------------------------------------------------------------
__global__ __launch_bounds__(256)
void colsum_partial_q(const unsigned char* __restrict__ W,
                      float* __restrict__ part)
{
    const int s0 = blockIdx.x * 4096 + threadIdx.x * 16;
    const int m0 = blockIdx.y * 128;
    float a[16];
#pragma unroll
    for (int j = 0; j < 16; ++j) a[j] = 0.f;
    for (int r = 0; r < 128; ++r) {
        ix4 u = *(const ix4*)(W + (size_t)(m0 + r) * MEMN + s0);
        const unsigned char* ub = (const unsigned char*)&u;
#pragma unroll
        for (int j = 0; j < 16; ++j) a[j] += q2f(ub[j]);
    }
#pragma unroll
    for (int q = 0; q < 4; ++q)
        *(fx4*)(part + (size_t)blockIdx.y * MEMN + s0 + q * 4) =
            *(fx4*)(a + q * 4);
}

// ---------------------------------------------------------------------------
// colsum_finalize: invc[s] = 1 / sum_c part[c][s].  grid 32 x 256 threads.
// ---------------------------------------------------------------------------
__global__ __launch_bounds__(256)
void colsum_finalize(const float* __restrict__ part, float* __restrict__ invc)
{
    const int s = blockIdx.x * 256 + threadIdx.x;
    float t = 0.f;
#pragma unroll 8
    for (int c = 0; c < 64; ++c) t += part[(size_t)c * MEMN + s];
    invc[s] = 1.0f / t;
}

// ---------------------------------------------------------------------------
// gemm8q: MX-fp8 NT GEMM, now used for ALL FOUR GEMMs.
// 128x256 tile, BK=128 (one mfma_scale_f32_16x16x128_f8f6f4 K-step), 512 thr
// = 8 waves (2Mx4N), wave tile 64x64 (acc[4][4]).  All MX scales = 1.0
// (e8m0 = 127) -> pure fp8 e4m3 math at 2x bf16 MFMA rate, half LDS bytes.
// Ring-3 LDS (144 KiB); round-3 counted-vmcnt ledger, L=6.
// Swizzle (validated r15): LDS granule g of row r holds src k-granule g^(r&7);
// fragment read for k-block fh reads granules (2fh)^(r&7),(2fh+1)^(r&7).
//   MODE 2: f32 out = c*oscale + add[idx]          (write PV; oscale=1/8192)
//   MODE 3: fp8 out = e4m3(exp(c*cscale + bias[col]))   (read logits)
//   MODE 4: fp8 out = e4m3(exp(c*cscale + bias[row]))   (write logits -> W^T)
//   MODE 5: f32 out = c / rowsum                   (read PV; ones-MFMA rowsum)
// cscale folds the 32x weight-quantization prescale out of the logits.
// ---------------------------------------------------------------------------
template <int MODE>
__global__ __launch_bounds__(512)
void gemm8q(const unsigned char* __restrict__ A,
            const unsigned char* __restrict__ B,
            const float* __restrict__ bias, const float* __restrict__ add,
            void* __restrict__ out,
            int N, int K, int nBN, float oscale, float cscale)
{
    constexpr int ASZ = 128 * 128;    // 16 KiB per A slot
    constexpr int BSZ = 256 * 128;    // 32 KiB per B slot
    __shared__ __align__(16) char smem[3 * (ASZ + BSZ)];   // 144 KiB
    char* const As = smem;
    char* const Bs = smem + 3 * ASZ;

    const int tid = threadIdx.x;
    const int wid = tid >> 6;
    const int ln  = tid & 63;
    const int fl  = ln & 15;
    const int fh  = ln >> 4;
    const int wr  = wid >> 2;          // 0..1 -> rows wr*64
    const int wc  = wid & 3;           // 0..3 -> cols wc*64

    const int nwg = gridDim.x;
    const int bid = blockIdx.x;
    const int wg  = (bid & 7) * (nwg >> 3) + (bid >> 3);
    const int tm  = (wg / nBN) * 128;
    const int tn  = (wg % nBN) * 256;
    const int NT  = K >> 7;            // K/128

    // staging: thread t covers row 64r + (t>>3), lds granule t&7;
    // src k-granule = (t&7)^((t>>3)&7)  (both-sides involution)
    const int trow = tid >> 3;
    const int tsrc = ((tid & 7) ^ ((tid >> 3) & 7)) * 16;
    const unsigned char* Ag[2];
    const unsigned char* Bg[4];
#pragma unroll
    for (int r = 0; r < 2; ++r)
        Ag[r] = A + (size_t)(tm + 64 * r + trow) * K + tsrc;
#pragma unroll
    for (int r = 0; r < 4; ++r)
        Bg[r] = B + (size_t)(tn + 64 * r + trow) * K + tsrc;

    auto stage = [&](int t) {
        const int s = t % 3;
        const size_t ko = (size_t)t * 128;
#pragma unroll
        for (int r = 0; r < 2; ++r)
            GLDS(Ag[r] + ko, As + s * ASZ + r * 8192 + wid * 1024);
#pragma unroll
        for (int r = 0; r < 4; ++r)
            GLDS(Bg[r] + ko, Bs + s * BSZ + r * 8192 + wid * 1024);
    };

    fx4 acc[4][4] = {};
    fx4 accs[4] = {};                  // MODE 5: row sums via ones-MFMA
    ix8 ones;
#pragma unroll
    for (int j = 0; j < 8; ++j) ones[j] = 0x38383838;   // fp8 e4m3 1.0 x4

    stage(0);
    stage(1);

    for (int t = 0; t < NT; ++t) {
        if (t == NT - 1) asm volatile("s_waitcnt vmcnt(0)" ::: "memory");
        else             asm volatile("s_waitcnt vmcnt(6)" ::: "memory");
        __builtin_amdgcn_s_barrier();
        MEMFENCE;
        if (t + 2 < NT) stage(t + 2);

        const char* Ab = As + (t % 3) * ASZ;
        const char* Bb = Bs + (t % 3) * BSZ;

        ix8 fa[4], fb[4];
#pragma unroll
        for (int mi = 0; mi < 4; ++mi) {
            const int r  = wr * 64 + mi * 16 + fl;
            const int g0 = (2 * fh) ^ (r & 7);
            const int g1 = (2 * fh + 1) ^ (r & 7);
            ix4 lo = *(const ix4*)(Ab + r * 128 + g0 * 16);
            ix4 hi = *(const ix4*)(Ab + r * 128 + g1 * 16);
            fa[mi][0] = lo[0]; fa[mi][1] = lo[1]; fa[mi][2] = lo[2]; fa[mi][3] = lo[3];
            fa[mi][4] = hi[0]; fa[mi][5] = hi[1]; fa[mi][6] = hi[2]; fa[mi][7] = hi[3];
        }
#pragma unroll
        for (int ni = 0; ni < 4; ++ni) {
            const int c  = wc * 64 + ni * 16 + fl;
            const int g0 = (2 * fh) ^ (c & 7);
            const int g1 = (2 * fh + 1) ^ (c & 7);
            ix4 lo = *(const ix4*)(Bb + c * 128 + g0 * 16);
            ix4 hi = *(const ix4*)(Bb + c * 128 + g1 * 16);
            fb[ni][0] = lo[0]; fb[ni][1] = lo[1]; fb[ni][2] = lo[2]; fb[ni][3] = lo[3];
            fb[ni][4] = hi[0]; fb[ni][5] = hi[1]; fb[ni][6] = hi[2]; fb[ni][7] = hi[3];
        }
        __builtin_amdgcn_s_setprio(1);
#pragma unroll
        for (int mi = 0; mi < 4; ++mi)
#pragma unroll
            for (int ni = 0; ni < 4; ++ni)
                acc[mi][ni] = __builtin_amdgcn_mfma_scale_f32_16x16x128_f8f6f4(
                    fa[mi], fb[ni], acc[mi][ni], 0, 0, 0, 127, 0, 127);
        if constexpr (MODE == 5) {
#pragma unroll
            for (int mi = 0; mi < 4; ++mi)
                accs[mi] = __builtin_amdgcn_mfma_scale_f32_16x16x128_f8f6f4(
                    fa[mi], ones, accs[mi], 0, 0, 0, 127, 0, 127);
        }
        __builtin_amdgcn_s_setprio(0);
    }

    // epilogue: C/D layout col = lane&15, row = (lane>>4)*4 + reg
#pragma unroll
    for (int mi = 0; mi < 4; ++mi) {
#pragma unroll
        for (int ni = 0; ni < 4; ++ni) {
            const int gr0 = tm + wr * 64 + mi * 16 + fh * 4;
            const int gc  = tn + wc * 64 + ni * 16 + fl;
            fx4 c = acc[mi][ni];
            if constexpr (MODE == 2) {
                float* O = (float*)out;
#pragma unroll
                for (int j = 0; j < 4; ++j) {
                    const size_t idx = (size_t)(gr0 + j) * N + gc;
                    O[idx] = c[j] * oscale + add[idx];
                }
            } else if constexpr (MODE == 3) {
                unsigned char* O = (unsigned char*)out;
                const float bv = bias[gc];
#pragma unroll
                for (int j = 0; j < 4; ++j)
                    O[(size_t)(gr0 + j) * N + gc] =
                        f2q(__expf(c[j] * cscale + bv));
            } else if constexpr (MODE == 4) {
                unsigned char* O = (unsigned char*)out;
#pragma unroll
                for (int j = 0; j < 4; ++j)
                    O[(size_t)(gr0 + j) * N + gc] =
                        f2q(__expf(c[j] * cscale + bias[gr0 + j]));
            } else {   // MODE 5: self-normalizing
                float* O = (float*)out;
#pragma unroll
                for (int j = 0; j < 4; ++j)
                    O[(size_t)(gr0 + j) * N + gc] = c[j] / accs[mi][j];
            }
        }
    }
}

// ---------------------------------------------------------------------------
// Orchestration — all-fp8 pipeline. ws layout (120 MiB used of 176):
//   xq    [8192,1024] fp8 @ 0        (8 MB, row-major x)
//   slot1 @ 16 MiB : rwq (8MB, 32*read_w) -> wwq (8MB, 32*write_w) ->
//                    part (2MB) + invc (32KB @ +4MiB)
//   slot2 @ 32 MiB : memT fp8 (8MB), then xT*invc*8192 fp8 (8MB)
//   Wq    @ 48 MiB : fp8 exp(read logits) [64MB], then fp8 exp(write logits)^T
// Weights are quantized as 32*w (escapes e4m3 subnormals); the logits GEMM
// epilogue multiplies the accumulator by cscale = 1/32 before exp.
// ---------------------------------------------------------------------------
extern "C" void kernel_launch(void* const* d_in, const int* in_sizes, int n_in,
                              void* d_out, int out_size, void* d_ws, size_t ws_size,
                              hipStream_t stream)
{
    const float* x       = (const float*)d_in[0];
    const float* memory  = (const float*)d_in[1];
    const float* read_w  = (const float*)d_in[2];
    const float* read_b  = (const float*)d_in[3];
    const float* write_w = (const float*)d_in[4];
    const float* write_b = (const float*)d_in[5];

    float* out_read = (float*)d_out;
    float* out_mem  = (float*)d_out + (size_t)MEMN * HID;

    char* p = (char*)d_ws;
    const size_t MiB = 1024 * 1024;
    unsigned char* xq    = (unsigned char*)(p + 0 * MiB);
    unsigned char* slot1 = (unsigned char*)(p + 16 * MiB);
    unsigned char* slot2 = (unsigned char*)(p + 32 * MiB);
    unsigned char* Wq    = (unsigned char*)(p + 48 * MiB);
    float*         part  = (float*)(p + 16 * MiB);     // after wwq dead
    float*         invc  = (float*)(p + 20 * MiB);

    // ---- read path ---------------------------------------------------------
    f32_to_fp8_vec<<<2048, 256, 0, stream>>>(x, xq, 1.0f);
    f32_to_fp8_vec<<<2048, 256, 0, stream>>>(read_w, slot1, 32.0f);
    transpose_f32_to_fp8<<<dim3(HID / 64, ROWS / 64), 256, 0, stream>>>(
        memory, slot2, nullptr, 1.0f, ROWS, HID);
    // Wq[s][m] = e4m3(exp((x.rw^T)/1 + rb))   [acc carries 32x -> cscale 1/32]
    gemm8q<3><<<(ROWS / 128) * (MEMN / 256), 512, 0, stream>>>(
        xq, slot1, read_b, nullptr, Wq, MEMN, HID, MEMN / 256, 1.0f, 1.0f / 32.0f);
    // out_read[s][h] = (sum_m Wq[s,m] memT[h,m]) / (sum_m Wq[s,m])
    gemm8q<5><<<(ROWS / 128) * (HID / 256), 512, 0, stream>>>(
        Wq, slot2, nullptr, nullptr, out_read, HID, MEMN, HID / 256, 1.0f, 1.0f);

    // ---- write path --------------------------------------------------------
    f32_to_fp8_vec<<<2048, 256, 0, stream>>>(write_w, slot1, 32.0f);
    // Wq^T[m][s] = e4m3(exp((ww.x^T)/1 + wb[m]))
    gemm8q<4><<<(MEMN / 128) * (ROWS / 256), 512, 0, stream>>>(
        slot1, xq, write_b, nullptr, Wq, ROWS, HID, ROWS / 256, 1.0f, 1.0f / 32.0f);
    colsum_partial_q<<<dim3(2, 64), 256, 0, stream>>>(Wq, part);
    colsum_finalize<<<32, 256, 0, stream>>>(part, invc);
    // xT[h][s] = e4m3(x[s][h] * invc[s] * 8192)
    transpose_f32_to_fp8<<<dim3(HID / 64, ROWS / 64), 256, 0, stream>>>(
        x, slot2, invc, 8192.0f, ROWS, HID);
    // out_mem[m][h] = memory[m,h] + (1/8192) * sum_s Wq^T[m,s] xT[h,s]
    gemm8q<2><<<(MEMN / 128) * (HID / 256), 512, 0, stream>>>(
        Wq, slot2, nullptr, memory, out_mem, HID, ROWS, HID / 256,
        1.0f / 8192.0f, 1.0f);
}

// Round 17
// 416.357 us; speedup vs baseline: 1.7513x; 1.1157x over previous
//
#include <hip/hip_runtime.h>
#include <hip/hip_bf16.h>
#include <hip/hip_fp8.h>

typedef __attribute__((ext_vector_type(4))) float  fx4;
typedef __attribute__((ext_vector_type(4))) int    ix4;
typedef __attribute__((ext_vector_type(8))) int    ix8;

#define ROWS 8192   // B*S
#define HID  1024
#define MEMN 8192

// global_load_lds, 16B per lane; LDS dest = wave-uniform base + lane*16
#define GLDS(gp, lp) __builtin_amdgcn_global_load_lds( \
    (const __attribute__((address_space(1))) void*)(gp), \
    (__attribute__((address_space(3))) void*)(lp), 16, 0, 0)

#define MEMFENCE asm volatile("" ::: "memory")

__device__ __forceinline__ unsigned char f2q(float f) {
    __hip_fp8_e4m3 q(f);
    return (unsigned char)q.__x;
}
__device__ __forceinline__ float q2f(unsigned char b) {
    __hip_fp8_e4m3 q;
    q.__x = (__hip_fp8_storage_t)b;
    return (float)q;
}

// ---------------------------------------------------------------------------
// fp32 -> fp8 e4m3 elementwise convert (16 elems/thread), value *= premul.
// ---------------------------------------------------------------------------
__global__ __launch_bounds__(256)
void f32_to_fp8_vec(const float* __restrict__ in,
                    unsigned char* __restrict__ out, float premul)
{
    const size_t i = ((size_t)blockIdx.x * 256 + threadIdx.x) * 16;
    unsigned char b[16];
#pragma unroll
    for (int q = 0; q < 4; ++q) {
        fx4 v = *(const fx4*)(in + i + q * 4);
        b[q * 4 + 0] = f2q(v[0] * premul);
        b[q * 4 + 1] = f2q(v[1] * premul);
        b[q * 4 + 2] = f2q(v[2] * premul);
        b[q * 4 + 3] = f2q(v[3] * premul);
    }
    *(ix4*)(out + i) = *(ix4*)b;
}

// ---------------------------------------------------------------------------
// fp32 [R][C] -> fp8 [C][R] transpose (64x64 tiles via LDS).
// scale != nullptr: multiply element (r,c) by scale[r]; then by premul.
// ---------------------------------------------------------------------------
__global__ __launch_bounds__(256)
void transpose_f32_to_fp8(const float* __restrict__ in,
                          unsigned char* __restrict__ out,
                          const float* __restrict__ scale, float premul,
                          int R, int C)
{
    __shared__ float t[64][65];
    const int tid = threadIdx.x;
    const int r0 = blockIdx.y * 64;
    const int c0 = blockIdx.x * 64;
    const int lr = tid >> 4;
    const int lc = (tid & 15) * 4;
#pragma unroll
    for (int p = 0; p < 4; ++p) {
        const int rr = p * 16 + lr;
        const fx4 v = *(const fx4*)(in + (size_t)(r0 + rr) * C + c0 + lc);
        t[rr][lc + 0] = v[0]; t[rr][lc + 1] = v[1];
        t[rr][lc + 2] = v[2]; t[rr][lc + 3] = v[3];
    }
    __syncthreads();
    const int oc = tid >> 2;
    const int ob = (tid & 3) * 16;
    unsigned char b[16];
#pragma unroll
    for (int j = 0; j < 16; ++j) {
        float v = t[ob + j][oc];
        if (scale) v *= scale[r0 + ob + j];
        b[j] = f2q(v * premul);
    }
    *(ix4*)(out + (size_t)(c0 + oc) * R + r0 + ob) = *(ix4*)b;
}

// ---------------------------------------------------------------------------
// colsum_partial_q: part[chunk][s] = sum over 128 rows of fp8 W[m][s].
// ---------------------------------------------------------------------------
__global__ __launch_bounds__(256)
void colsum_partial_q(const unsigned char* __restrict__ W,
                      float* __restrict__ part)
{
    const int s0 = blockIdx.x * 4096 + threadIdx.x * 16;
    const int m0 = blockIdx.y * 128;
    float a[16];
#pragma unroll
    for (int j = 0; j < 16; ++j) a[j] = 0.f;
    for (int r = 0; r < 128; ++r) {
        ix4 u = *(const ix4*)(W + (size_t)(m0 + r) * MEMN + s0);
        const unsigned char* ub = (const unsigned char*)&u;
#pragma unroll
        for (int j = 0; j < 16; ++j) a[j] += q2f(ub[j]);
    }
#pragma unroll
    for (int q = 0; q < 4; ++q)
        *(fx4*)(part + (size_t)blockIdx.y * MEMN + s0 + q * 4) =
            *(fx4*)(a + q * 4);
}

// ---------------------------------------------------------------------------
// colsum_finalize: invc[s] = 1 / sum_c part[c][s].
// ---------------------------------------------------------------------------
__global__ __launch_bounds__(256)
void colsum_finalize(const float* __restrict__ part, float* __restrict__ invc)
{
    const int s = blockIdx.x * 256 + threadIdx.x;
    float t = 0.f;
#pragma unroll 8
    for (int c = 0; c < 64; ++c) t += part[(size_t)c * MEMN + s];
    invc[s] = 1.0f / t;
}

// ---------------------------------------------------------------------------
// gemm8q: MX-fp8 NT GEMM (all four GEMMs). 128x256 tile, BK=128, 512 thr =
// 8 waves (2Mx4N), wave tile 64x64. Ring-3 LDS (144 KiB); counted-vmcnt
// ledger (L=6).  r17 changes vs r16:
//  (1) ROTATED granule swizzle: LDS pos p of row r holds k-granule
//      rot_inv(p ^ (r&7)), rot(k) = (k>>1)|((k&1)<<2).  A fragment's two
//      16B reads land at g0 = fh^(r&7) and g0^4 (64B apart, different bank
//      halves) instead of adjacent granules -> targets the measured 8.4M
//      SQ_LDS_BANK_CONFLICT (4 per ds_read_b128).
//  (2) L2 rasterization: column-groups of G=min(8,nBN) sweep all rows
//      before advancing (B sub-panel 2MB fits per-XCD L2).
// Modes: 2 = f32 c*oscale+add; 3 = fp8 exp(c*cscale+bias[col]);
//        4 = fp8 exp(c*cscale+bias[row]); 5 = f32 c/rowsum (ones-MFMA).
// ---------------------------------------------------------------------------
template <int MODE>
__global__ __launch_bounds__(512)
void gemm8q(const unsigned char* __restrict__ A,
            const unsigned char* __restrict__ B,
            const float* __restrict__ bias, const float* __restrict__ add,
            void* __restrict__ out,
            int N, int K, int nBN, float oscale, float cscale)
{
    constexpr int ASZ = 128 * 128;    // 16 KiB per A slot
    constexpr int BSZ = 256 * 128;    // 32 KiB per B slot
    __shared__ __align__(16) char smem[3 * (ASZ + BSZ)];   // 144 KiB
    char* const As = smem;
    char* const Bs = smem + 3 * ASZ;

    const int tid = threadIdx.x;
    const int wid = tid >> 6;
    const int ln  = tid & 63;
    const int fl  = ln & 15;
    const int fh  = ln >> 4;
    const int wr  = wid >> 2;          // 0..1 -> rows wr*64
    const int wc  = wid & 3;           // 0..3 -> cols wc*64

    // XCD swizzle + L2-friendly rasterization (col-groups of G sweep rows)
    const int nwg = gridDim.x;
    const int bid = blockIdx.x;
    const int wg  = (bid & 7) * (nwg >> 3) + (bid >> 3);
    const int G   = (nBN >= 8) ? 8 : nBN;
    const int nBM = nwg / nBN;
    const int grp = nBM * G;
    const int cg  = wg / grp;
    const int rem = wg % grp;
    const int tm  = (rem / G) * 128;
    const int tn  = (cg * G + rem % G) * 256;
    const int NT  = K >> 7;            // K/128

    // staging: thread t -> row 64*round + (t>>3), LDS granule t&7.
    // source k-granule = rot_inv((t&7) ^ ((t>>3)&7))
    const int trow = tid >> 3;
    const int qq   = (tid & 7) ^ ((tid >> 3) & 7);
    const int tsrc = (((qq & 3) << 1) | (qq >> 2)) * 16;
    const unsigned char* Ag[2];
    const unsigned char* Bg[4];
#pragma unroll
    for (int r = 0; r < 2; ++r)
        Ag[r] = A + (size_t)(tm + 64 * r + trow) * K + tsrc;
#pragma unroll
    for (int r = 0; r < 4; ++r)
        Bg[r] = B + (size_t)(tn + 64 * r + trow) * K + tsrc;

    auto stage = [&](int t) {
        const int s = t % 3;
        const size_t ko = (size_t)t * 128;
#pragma unroll
        for (int r = 0; r < 2; ++r)
            GLDS(Ag[r] + ko, As + s * ASZ + r * 8192 + wid * 1024);
#pragma unroll
        for (int r = 0; r < 4; ++r)
            GLDS(Bg[r] + ko, Bs + s * BSZ + r * 8192 + wid * 1024);
    };

    fx4 acc[4][4] = {};
    fx4 accs[4] = {};                  // MODE 5: row sums via ones-MFMA
    ix8 ones;
#pragma unroll
    for (int j = 0; j < 8; ++j) ones[j] = 0x38383838;   // fp8 e4m3 1.0 x4

    stage(0);
    stage(1);

    for (int t = 0; t < NT; ++t) {
        if (t == NT - 1) asm volatile("s_waitcnt vmcnt(0)" ::: "memory");
        else             asm volatile("s_waitcnt vmcnt(6)" ::: "memory");
        __builtin_amdgcn_s_barrier();
        MEMFENCE;
        if (t + 2 < NT) stage(t + 2);

        const char* Ab = As + (t % 3) * ASZ;
        const char* Bb = Bs + (t % 3) * BSZ;

        ix8 fa[4], fb[4];
#pragma unroll
        for (int mi = 0; mi < 4; ++mi) {
            const int r  = wr * 64 + mi * 16 + fl;
            const int g0 = fh ^ (r & 7);           // rot(2fh)   ^ (r&7)
            const int g1 = g0 ^ 4;                 // rot(2fh+1) ^ (r&7)
            ix4 lo = *(const ix4*)(Ab + r * 128 + g0 * 16);
            ix4 hi = *(const ix4*)(Ab + r * 128 + g1 * 16);
            fa[mi][0] = lo[0]; fa[mi][1] = lo[1]; fa[mi][2] = lo[2]; fa[mi][3] = lo[3];
            fa[mi][4] = hi[0]; fa[mi][5] = hi[1]; fa[mi][6] = hi[2]; fa[mi][7] = hi[3];
        }
#pragma unroll
        for (int ni = 0; ni < 4; ++ni) {
            const int c  = wc * 64 + ni * 16 + fl;
            const int g0 = fh ^ (c & 7);
            const int g1 = g0 ^ 4;
            ix4 lo = *(const ix4*)(Bb + c * 128 + g0 * 16);
            ix4 hi = *(const ix4*)(Bb + c * 128 + g1 * 16);
            fb[ni][0] = lo[0]; fb[ni][1] = lo[1]; fb[ni][2] = lo[2]; fb[ni][3] = lo[3];
            fb[ni][4] = hi[0]; fb[ni][5] = hi[1]; fb[ni][6] = hi[2]; fb[ni][7] = hi[3];
        }
        __builtin_amdgcn_s_setprio(1);
#pragma unroll
        for (int mi = 0; mi < 4; ++mi)
#pragma unroll
            for (int ni = 0; ni < 4; ++ni)
                acc[mi][ni] = __builtin_amdgcn_mfma_scale_f32_16x16x128_f8f6f4(
                    fa[mi], fb[ni], acc[mi][ni], 0, 0, 0, 127, 0, 127);
        if constexpr (MODE == 5) {
#pragma unroll
            for (int mi = 0; mi < 4; ++mi)
                accs[mi] = __builtin_amdgcn_mfma_scale_f32_16x16x128_f8f6f4(
                    fa[mi], ones, accs[mi], 0, 0, 0, 127, 0, 127);
        }
        __builtin_amdgcn_s_setprio(0);
    }

    // epilogue: C/D layout col = lane&15, row = (lane>>4)*4 + reg
#pragma unroll
    for (int mi = 0; mi < 4; ++mi) {
#pragma unroll
        for (int ni = 0; ni < 4; ++ni) {
            const int gr0 = tm + wr * 64 + mi * 16 + fh * 4;
            const int gc  = tn + wc * 64 + ni * 16 + fl;
            fx4 c = acc[mi][ni];
            if constexpr (MODE == 2) {
                float* O = (float*)out;
#pragma unroll
                for (int j = 0; j < 4; ++j) {
                    const size_t idx = (size_t)(gr0 + j) * N + gc;
                    O[idx] = c[j] * oscale + add[idx];
                }
            } else if constexpr (MODE == 3) {
                unsigned char* O = (unsigned char*)out;
                const float bv = bias[gc];
#pragma unroll
                for (int j = 0; j < 4; ++j)
                    O[(size_t)(gr0 + j) * N + gc] =
                        f2q(__expf(c[j] * cscale + bv));
            } else if constexpr (MODE == 4) {
                unsigned char* O = (unsigned char*)out;
#pragma unroll
                for (int j = 0; j < 4; ++j)
                    O[(size_t)(gr0 + j) * N + gc] =
                        f2q(__expf(c[j] * cscale + bias[gr0 + j]));
            } else {   // MODE 5: self-normalizing
                float* O = (float*)out;
#pragma unroll
                for (int j = 0; j < 4; ++j)
                    O[(size_t)(gr0 + j) * N + gc] = c[j] / accs[mi][j];
            }
        }
    }
}

// ---------------------------------------------------------------------------
// Orchestration — all-fp8 pipeline (layout unchanged from r16):
//   xq @ 0 (8MB) | slot1 @ 16MiB (rwq/wwq -> part+invc) | slot2 @ 32MiB
//   (memT fp8 -> xT*invc*8192 fp8) | Wq @ 48MiB (64MB)
// Weights quantized as 32*w (escape e4m3 subnormals); logits epilogue
// multiplies acc by cscale = 1/32 before exp.
// ---------------------------------------------------------------------------
extern "C" void kernel_launch(void* const* d_in, const int* in_sizes, int n_in,
                              void* d_out, int out_size, void* d_ws, size_t ws_size,
                              hipStream_t stream)
{
    const float* x       = (const float*)d_in[0];
    const float* memory  = (const float*)d_in[1];
    const float* read_w  = (const float*)d_in[2];
    const float* read_b  = (const float*)d_in[3];
    const float* write_w = (const float*)d_in[4];
    const float* write_b = (const float*)d_in[5];

    float* out_read = (float*)d_out;
    float* out_mem  = (float*)d_out + (size_t)MEMN * HID;

    char* p = (char*)d_ws;
    const size_t MiB = 1024 * 1024;
    unsigned char* xq    = (unsigned char*)(p + 0 * MiB);
    unsigned char* slot1 = (unsigned char*)(p + 16 * MiB);
    unsigned char* slot2 = (unsigned char*)(p + 32 * MiB);
    unsigned char* Wq    = (unsigned char*)(p + 48 * MiB);
    float*         part  = (float*)(p + 16 * MiB);     // after wwq dead
    float*         invc  = (float*)(p + 20 * MiB);

    // ---- read path ---------------------------------------------------------
    f32_to_fp8_vec<<<2048, 256, 0, stream>>>(x, xq, 1.0f);
    f32_to_fp8_vec<<<2048, 256, 0, stream>>>(read_w, slot1, 32.0f);
    transpose_f32_to_fp8<<<dim3(HID / 64, ROWS / 64), 256, 0, stream>>>(
        memory, slot2, nullptr, 1.0f, ROWS, HID);
    // Wq[s][m] = e4m3(exp((x.rw^T)/32*32 + rb))
    gemm8q<3><<<(ROWS / 128) * (MEMN / 256), 512, 0, stream>>>(
        xq, slot1, read_b, nullptr, Wq, MEMN, HID, MEMN / 256, 1.0f, 1.0f / 32.0f);
    // out_read[s][h] = (sum_m Wq[s,m] memT[h,m]) / (sum_m Wq[s,m])
    gemm8q<5><<<(ROWS / 128) * (HID / 256), 512, 0, stream>>>(
        Wq, slot2, nullptr, nullptr, out_read, HID, MEMN, HID / 256, 1.0f, 1.0f);

    // ---- write path --------------------------------------------------------
    f32_to_fp8_vec<<<2048, 256, 0, stream>>>(write_w, slot1, 32.0f);
    // Wq^T[m][s] = e4m3(exp((ww.x^T) + wb[m]))
    gemm8q<4><<<(MEMN / 128) * (ROWS / 256), 512, 0, stream>>>(
        slot1, xq, write_b, nullptr, Wq, ROWS, HID, ROWS / 256, 1.0f, 1.0f / 32.0f);
    colsum_partial_q<<<dim3(2, 64), 256, 0, stream>>>(Wq, part);
    colsum_finalize<<<32, 256, 0, stream>>>(part, invc);
    // xT[h][s] = e4m3(x[s][h] * invc[s] * 8192)
    transpose_f32_to_fp8<<<dim3(HID / 64, ROWS / 64), 256, 0, stream>>>(
        x, slot2, invc, 8192.0f, ROWS, HID);
    // out_mem[m][h] = memory[m,h] + (1/8192) * sum_s Wq^T[m,s] xT[h,s]
    gemm8q<2><<<(MEMN / 128) * (HID / 256), 512, 0, stream>>>(
        Wq, slot2, nullptr, memory, out_mem, HID, ROWS, HID / 256,
        1.0f / 8192.0f, 1.0f);
}